// Round 1
// 179.860 us; speedup vs baseline: 1.0522x; 1.0522x over previous
//
#include <hip/hip_runtime.h>
#include <hip/hip_bf16.h>

#define CIN   256
#define COUT  32
#define IMG_H 96
#define IMG_W 96
#define HW    (IMG_H*IMG_W)
#define NB    2
#define NV    4
#define VSZ   64
#define NVOX  (VSZ*VSZ*VSZ)

typedef __attribute__((ext_vector_type(2))) float f32x2;

// Kernel 1: 1x1 conv -> channel-last bf16 [b,v,h,w,c].  (unchanged this round)
// Block = 256 thr = 4 waves over the same 64 px; wave og owns couts
// [og*8, og*8+8). Weights are wave-uniform -> forced through the SCALAR path
// (s_load_dwordx8, SGPR-sourced FMAs): zero LDS traffic. x-loads batched
// 8-deep for MLP. No __shared__, no barriers.
__global__ __launch_bounds__(256) void conv1x1_kernel(
    const float* __restrict__ features,   // [B,V,CIN,H,W] fp32
    const float* __restrict__ Wp,         // [COUT,CIN]
    const float* __restrict__ bp,         // [COUT]
    __hip_bfloat16* __restrict__ out)     // [B,V,H,W,COUT] bf16
{
    const int og   = __builtin_amdgcn_readfirstlane((threadIdx.x >> 6) & 3);
    const int lane = threadIdx.x & 63;
    const int bv   = blockIdx.y;
    const int px   = blockIdx.x*64 + lane;
    const float* f     = features + (size_t)bv*CIN*HW + px;
    const float* wbase = Wp + (size_t)og*8*CIN;     // uniform -> scalar base

    float acc[8];
    #pragma unroll
    for (int j = 0; j < 8; ++j) acc[j] = bp[og*8 + j];   // uniform -> s_load

    for (int cc = 0; cc < CIN; cc += 8) {
        float x[8];
        #pragma unroll
        for (int i = 0; i < 8; ++i)                  // 8 indep coalesced loads
            x[i] = f[(size_t)(cc + i)*HW];
        #pragma unroll
        for (int i = 0; i < 8; ++i) {
            #pragma unroll
            for (int j = 0; j < 8; ++j)              // v_fmac v, s, v
                acc[j] += x[i] * wbase[(size_t)j*CIN + cc + i];
        }
    }

    union { uint4 u4; __hip_bfloat16 h[8]; } pk;
    #pragma unroll
    for (int j = 0; j < 8; ++j) pk.h[j] = __float2bfloat16(acc[j]);
    *(uint4*)(out + ((size_t)(bv*HW + px))*COUT + og*8) = pk.u4;
}

// Kernel 2 (R5): voxel-per-lane. Each lane owns ONE voxel and all 32
// channels (4 chunks of 8). Rationale (rocprof R4): VALUBusy ~80%,
// FETCH tiny (cache-resident gathers) -> VALU-issue bound, and the old
// 4-lanes-per-voxel split executed the ~230-op projection/weight pipeline
// 4x redundantly (~1/3 of total issue). Now: projection once per voxel;
// 16 corner offsets computed once, chunk advance folds into the load's
// 13-bit imm offset; bilinear accumulate in packed f32x2 (v_pk_fma_f32);
// stores are lane-contiguous per channel -> no LDS transpose, no barrier.
__global__ __launch_bounds__(256) void volgen_kernel(
    const __hip_bfloat16* __restrict__ feats,  // [B,V,H,W,COUT] bf16
    const float* __restrict__ proj,            // [B,V,3,4]
    const float* __restrict__ coords,          // [B,NVOX,3]
    float* __restrict__ out)                   // [B,COUT,NVOX]
{
    const int tid = threadIdx.x;
    const int b   = blockIdx.y;
    const int n   = blockIdx.x*256 + tid;

    const float* cp = coords + ((size_t)b*NVOX + n)*3;
    const float X = cp[0], Y = cp[1], Z = cp[2];

    int   off[NV][4];
    float wgt[NV][4];
    #pragma unroll
    for (int v = 0; v < NV; ++v) {
        const float* P = proj + (size_t)(b*NV + v)*12;   // uniform -> scalar
        const float wz = P[8]*X + P[9]*Y + P[10]*Z + P[11];
        const bool  vz = wz > 0.f;
        const float rz = __builtin_amdgcn_rcpf(wz);
        float px = (P[0]*X + P[1]*Y + P[2]*Z + P[3]) * rz * (95.f/96.f);
        float py = (P[4]*X + P[5]*Y + P[6]*Z + P[7]) * rz * (95.f/96.f);
        px = vz ? px : 0.f;  py = vz ? py : 0.f;
        px = fminf(fmaxf(px, -1.0e6f), 1.0e6f);
        py = fminf(fmaxf(py, -1.0e6f), 1.0e6f);
        const float fx0 = floorf(px), fy0 = floorf(py);
        const int x0 = (int)fx0, y0 = (int)fy0, x1 = x0+1, y1 = y0+1;
        const float wx1 = px - fx0, wx0 = 1.f - wx1;
        const float wy1 = py - fy0, wy0 = 1.f - wy1;
        const bool vx0 = (unsigned)x0 < (unsigned)IMG_W;
        const bool vx1 = (unsigned)x1 < (unsigned)IMG_W;
        const bool vy0 = (unsigned)y0 < (unsigned)IMG_H;
        const bool vy1 = (unsigned)y1 < (unsigned)IMG_H;
        const int cx0 = min(max(x0, 0), IMG_W-1), cx1 = min(max(x1, 0), IMG_W-1);
        const int cy0 = min(max(y0, 0), IMG_H-1), cy1 = min(max(y1, 0), IMG_H-1);
        const int base = ((b*NV + v)*HW)*COUT;           // uniform
        off[v][0] = base + (cy0*IMG_W + cx0)*COUT;  wgt[v][0] = (vz & vx0 & vy0) ? wx0*wy0 : 0.f;
        off[v][1] = base + (cy0*IMG_W + cx1)*COUT;  wgt[v][1] = (vz & vx1 & vy0) ? wx1*wy0 : 0.f;
        off[v][2] = base + (cy1*IMG_W + cx0)*COUT;  wgt[v][2] = (vz & vx0 & vy1) ? wx0*wy1 : 0.f;
        off[v][3] = base + (cy1*IMG_W + cx1)*COUT;  wgt[v][3] = (vz & vx1 & vy1) ? wx1*wy1 : 0.f;
    }

    const size_t ob = (size_t)b*COUT*NVOX + n;

    #pragma unroll
    for (int ch0 = 0; ch0 < COUT; ch0 += 8) {
        f32x2 A2[4], B2[4];
        #pragma unroll
        for (int k = 0; k < 4; ++k) { A2[k] = (f32x2)(0.f); B2[k] = (f32x2)(0.f); }

        #pragma unroll
        for (int v = 0; v < NV; ++v) {
            uint4 t[4];
            #pragma unroll
            for (int c = 0; c < 4; ++c)            // 4 gathers in flight
                t[c] = *(const uint4*)(feats + off[v][c] + ch0);

            f32x2 s2[4];
            #pragma unroll
            for (int k = 0; k < 4; ++k) s2[k] = (f32x2)(0.f);

            #pragma unroll
            for (int c = 0; c < 4; ++c) {
                const f32x2 w2 = (f32x2)(wgt[v][c]);
                const unsigned tu[4] = { t[c].x, t[c].y, t[c].z, t[c].w };
                #pragma unroll
                for (int k = 0; k < 4; ++k) {      // packed fma: 2 ch / instr
                    f32x2 f2;
                    f2.x = __uint_as_float(tu[k] << 16);
                    f2.y = __uint_as_float(tu[k] & 0xffff0000u);
                    s2[k] += w2 * f2;
                }
            }
            #pragma unroll
            for (int k = 0; k < 4; ++k) {
                f32x2 e2;
                e2.x = __expf(s2[k].x);            // all-zero weights -> e=1
                e2.y = __expf(s2[k].y);
                A2[k] += e2;
                B2[k] += s2[k]*e2;
            }
        }

        #pragma unroll
        for (int k = 0; k < 4; ++k) {              // coalesced: lanes = consec voxels
            out[ob + (size_t)(ch0 + 2*k    )*NVOX] = B2[k].x * __builtin_amdgcn_rcpf(A2[k].x);
            out[ob + (size_t)(ch0 + 2*k + 1)*NVOX] = B2[k].y * __builtin_amdgcn_rcpf(A2[k].y);
        }
    }
}

extern "C" void kernel_launch(void* const* d_in, const int* in_sizes, int n_in,
                              void* d_out, int out_size, void* d_ws, size_t ws_size,
                              hipStream_t stream)
{
    const float* features = (const float*)d_in[0];   // [2,4,256,96,96]
    const float* proj     = (const float*)d_in[1];   // [2,4,3,4]
    const float* coords   = (const float*)d_in[2];   // [2,64,64,64,3]
    const float* Wp       = (const float*)d_in[3];   // [32,256]
    const float* bp       = (const float*)d_in[4];   // [32]
    float* out = (float*)d_out;                      // [2,32,64,64,64]
    __hip_bfloat16* featsT = (__hip_bfloat16*)d_ws;  // [2,4,96,96,32] bf16 = 4.72 MB

    hipLaunchKernelGGL(conv1x1_kernel, dim3(HW/64, NB*NV), dim3(256), 0, stream,
                       features, Wp, bp, featsT);
    hipLaunchKernelGGL(volgen_kernel, dim3(NVOX/256, NB), dim3(256), 0, stream,
                       featsT, proj, coords, out);
}